// Round 6
// baseline (368.951 us; speedup 1.0000x reference)
//
#include <hip/hip_runtime.h>

typedef __attribute__((ext_vector_type(8))) short short8v;  // 8 bf16 / 4 VGPR
typedef __attribute__((ext_vector_type(4))) int   int4v;
typedef __attribute__((ext_vector_type(4))) float f32x4;

#define NBLOCKS 1024
#define WPB 4            // waves per block
#define NSLOT 64         // per-wave LDS bag slots (data max ~27)

__device__ __forceinline__ unsigned short f2bf(float f) {
  unsigned u = __builtin_bit_cast(unsigned, f);
  unsigned r = u + 0x7FFFu + ((u >> 16) & 1u);
  return (unsigned short)(r >> 16);
}
__device__ __forceinline__ float bf2f(unsigned short h) {
  unsigned u = ((unsigned)h) << 16;
  return __builtin_bit_cast(float, u);
}

template <int CTRL>
__device__ __forceinline__ float dpp_add(float s) {
  int t = __builtin_amdgcn_update_dpp(0, __builtin_bit_cast(int, s), CTRL, 0xF, 0xF, true);
  return s + __builtin_bit_cast(float, t);
}

// One wave owns a contiguous run of 64-row chunks (8 KiB each).
// Global loads are lane-ascending float4 (perfectly coalesced, mergeable into
// full cache lines); the XOR swizzle is applied on the ds_write side (per-lane
// LDS addresses are free), so fragment ds_reads land conflict-free in exactly
// the layout already correctness-proven in v3. Chunk c+1 is register-
// prefetched under chunk c's full compute (MFMA+epilogue hides HBM latency).
__global__ void __launch_bounds__(256, 3) bag_mlp_v4(
    const float* __restrict__ x, const int* __restrict__ ids,
    const float* __restrict__ W1, const float* __restrict__ b1,
    const float* __restrict__ W2,
    float* __restrict__ bag_sum, int nchunks, int cpw, int nbags)
{
  __shared__ __align__(16) char stage[WPB][8192];   // 64 rows x 128 B per wave
  __shared__ float sacc[WPB][NSLOT];

  const int wid  = threadIdx.x >> 6;
  const int lane = threadIdx.x & 63;
  const int lm = lane & 15, lg = lane >> 4;
  const int w = blockIdx.x * WPB + wid;

  const int c_begin = w * cpw;
  if (c_begin >= nchunks) return;                   // wave-uniform
  const int c_end = min(c_begin + cpw, nchunks);

  sacc[wid][lane] = 0.f;                            // NSLOT == 64 == lanes
  const int base_id = ids[(size_t)c_begin * 64];

  // ---- W1 as B-fragments (RNE hi/lo bf16 split); k-map shared with A ----
  short8v bh[4], bl[4];
#pragma unroll
  for (int nt = 0; nt < 4; ++nt) {
    const int col = lm + 16 * nt;
#pragma unroll
    for (int e = 0; e < 8; ++e) {
      const int k = 16 * (e >> 2) + 4 * lg + (e & 3);
      const float f = W1[k * 64 + col];
      const unsigned short h = f2bf(f);
      bh[nt][e] = (short)h;
      bl[nt][e] = (short)f2bf(f - bf2f(h));
    }
  }
  float b1c[4], w2c[4];
#pragma unroll
  for (int nt = 0; nt < 4; ++nt) {
    b1c[nt] = b1[lm + 16 * nt];
    w2c[nt] = W2[lm + 16 * nt];
  }

  // row this lane's myval corresponds to (bijection over 64)
  const int R_perm = ((lm >> 2) << 4) + (lg << 2) + (lm & 3);
  // ds_write address: row = lane>>3 (+8 per q), slot XOR-swizzled by row&7
  const int wr_base = (lane >> 3) * 128 + ((((lane & 7) ^ ((lane >> 3) & 7))) << 4);
  char* sb = &stage[wid][0];

  // ---- prologue: load chunk c_begin into registers (lane-ascending) ----
  float4 r0, r1, r2, r3, r4, r5, r6, r7;
  int myid;
  {
    const float4* src = (const float4*)(x + (size_t)c_begin * 2048) + lane;
    r0 = src[0];   r1 = src[64];  r2 = src[128]; r3 = src[192];
    r4 = src[256]; r5 = src[320]; r6 = src[384]; r7 = src[448];
    myid = ids[(size_t)c_begin * 64 + R_perm];
  }

  for (int c = c_begin; c < c_end; ++c) {
    // WAR: prior iteration's ds_reads drained before overwriting the buffer
    asm volatile("s_waitcnt lgkmcnt(0)" ::: "memory");
    __builtin_amdgcn_sched_barrier(0);

    // ---- stage chunk c: ds_write_b128, write-side XOR swizzle ----
    *(float4*)(sb + wr_base)        = r0;
    *(float4*)(sb + wr_base + 1024) = r1;
    *(float4*)(sb + wr_base + 2048) = r2;
    *(float4*)(sb + wr_base + 3072) = r3;
    *(float4*)(sb + wr_base + 4096) = r4;
    *(float4*)(sb + wr_base + 5120) = r5;
    *(float4*)(sb + wr_base + 6144) = r6;
    *(float4*)(sb + wr_base + 7168) = r7;

    // ---- issue prefetch of chunk c+1 (hidden under this chunk's compute) ----
    const int cnext = (c + 1 < c_end) ? c + 1 : c;   // tail refetch = L2 hit
    const float4* nsrc = (const float4*)(x + (size_t)cnext * 2048) + lane;
    float4 n0 = nsrc[0],   n1 = nsrc[64],  n2 = nsrc[128], n3 = nsrc[192];
    float4 n4 = nsrc[256], n5 = nsrc[320], n6 = nsrc[384], n7 = nsrc[448];
    const int nid = ids[(size_t)cnext * 64 + R_perm];

    // ---- read fragments + truncation-split conversion ----
    short8v ah[4], al[4];
#pragma unroll
    for (int t = 0; t < 4; ++t) {
      const int rb = t * 2048 + lm * 128;
      const float4 va = *(const float4*)(sb + rb + ((lg ^ (lm & 7)) << 4));
      const float4 vb = *(const float4*)(sb + rb + (((lg + 4) ^ (lm & 7)) << 4));
      int4v ahi, ali;
      const float pf[8] = {va.x, va.y, va.z, va.w, vb.x, vb.y, vb.z, vb.w};
#pragma unroll
      for (int p = 0; p < 4; ++p) {
        const float f0 = pf[2 * p], f1 = pf[2 * p + 1];
        const unsigned u0 = __builtin_bit_cast(unsigned, f0);
        const unsigned u1 = __builtin_bit_cast(unsigned, f1);
        const unsigned h0 = u0 & 0xFFFF0000u, h1 = u1 & 0xFFFF0000u;
        ahi[p] = (int)((u0 >> 16) | h1);               // [bf16(f1):bf16(f0)]
        const float lo0 = f0 - __builtin_bit_cast(float, h0);   // exact
        const float lo1 = f1 - __builtin_bit_cast(float, h1);   // exact
        const unsigned lu0 = __builtin_bit_cast(unsigned, lo0);
        const unsigned lu1 = __builtin_bit_cast(unsigned, lo1);
        ali[p] = (int)((lu0 >> 16) | (lu1 & 0xFFFF0000u));
      }
      ah[t] = __builtin_bit_cast(short8v, ahi);
      al[t] = __builtin_bit_cast(short8v, ali);
    }

    // ---- 4 tiles: 3-term split MFMA + relu-dot epilogue ----
    float myval = 0.f;
#pragma unroll
    for (int t = 0; t < 4; ++t) {
      f32x4 acc[4];
#pragma unroll
      for (int nt = 0; nt < 4; ++nt)
        acc[nt] = (f32x4){b1c[nt], b1c[nt], b1c[nt], b1c[nt]};   // fold bias
#pragma unroll
      for (int nt = 0; nt < 4; ++nt) {
        acc[nt] = __builtin_amdgcn_mfma_f32_16x16x32_bf16(ah[t], bh[nt], acc[nt], 0, 0, 0);
        acc[nt] = __builtin_amdgcn_mfma_f32_16x16x32_bf16(ah[t], bl[nt], acc[nt], 0, 0, 0);
        acc[nt] = __builtin_amdgcn_mfma_f32_16x16x32_bf16(al[t], bh[nt], acc[nt], 0, 0, 0);
      }
      // D layout: acc[nt][r] = h[row=16t+4lg+r][col=lm+16nt]
      float ps[4];
#pragma unroll
      for (int r = 0; r < 4; ++r) {
        float s = 0.f;
#pragma unroll
        for (int nt = 0; nt < 4; ++nt)
          s = fmaf(fmaxf(acc[nt][r], 0.f), w2c[nt], s);
        ps[r] = s;
      }
#pragma unroll
      for (int r = 0; r < 4; ++r) {
        ps[r] = dpp_add<0xB1>(ps[r]);    // quad_perm xor1
        ps[r] = dpp_add<0x4E>(ps[r]);    // quad_perm xor2
        ps[r] = dpp_add<0x124>(ps[r]);   // row_ror:4
        ps[r] = dpp_add<0x128>(ps[r]);   // row_ror:8
      }
      const float t01 = (lm & 1) ? ps[1] : ps[0];
      const float t23 = (lm & 1) ? ps[3] : ps[2];
      const float sel = (lm & 2) ? t23 : t01;
      if ((lm >> 2) == t) myval = sel;   // this lane's row = R_perm
    }

    // ---- per-wave LDS bag accumulation (no global atomics in loop) ----
    const int slot = myid - base_id;                 // >=0 (sorted ids)
    if (slot < NSLOT) atomicAdd(&sacc[wid][slot], myval);
    else              atomicAdd(&bag_sum[myid], myval);  // never taken here

    // rotate prefetch -> current
    r0 = n0; r1 = n1; r2 = n2; r3 = n3;
    r4 = n4; r5 = n5; r6 = n6; r7 = n7;
    myid = nid;
  }

  // ---- flush: ~27 live slots per wave ----
  const float v = sacc[wid][lane];
  const int bag = base_id + lane;
  if (v != 0.f && bag < nbags) atomicAdd(&bag_sum[bag], v);
}

// start[b] = first index of bag b (every bag present per generator)
__global__ void __launch_bounds__(256) bag_start_kernel(
    const int* __restrict__ ids, int* __restrict__ start, int n)
{
  for (int i = blockIdx.x * blockDim.x + threadIdx.x; i < n;
       i += gridDim.x * blockDim.x) {
    const int id = ids[i];
    if (i == 0 || ids[i - 1] != id) start[id] = i;
  }
}

__global__ void __launch_bounds__(256) finalize_kernel(
    const float* __restrict__ bag_sum, const int* __restrict__ start,
    const float* __restrict__ b2, float* __restrict__ out, int nbags, int n)
{
  const int b = blockIdx.x * blockDim.x + threadIdx.x;
  if (b >= nbags) return;
  const int s = start[b];
  const int e = (b + 1 < nbags) ? start[b + 1] : n;
  out[b] = bag_sum[b] / (float)(e - s) + b2[0];
}

extern "C" void kernel_launch(void* const* d_in, const int* in_sizes, int n_in,
                              void* d_out, int out_size, void* d_ws, size_t ws_size,
                              hipStream_t stream)
{
  const float* x   = (const float*)d_in[0];
  const int*   ids = (const int*)d_in[1];
  const float* W1  = (const float*)d_in[2];
  const float* b1  = (const float*)d_in[3];
  const float* W2  = (const float*)d_in[4];
  const float* b2  = (const float*)d_in[5];
  float* out = (float*)d_out;

  const int n     = in_sizes[0] / 32;   // N_INST (divisible by 64)
  const int nbags = out_size;           // NUM_BAGS

  float* bag_sum = (float*)d_ws;
  int*   start   = (int*)(bag_sum + nbags);

  (void)hipMemsetAsync(bag_sum, 0, (size_t)nbags * sizeof(float), stream);

  const int nchunks = n / 64;
  const int nwaves  = NBLOCKS * WPB;
  const int cpw     = (nchunks + nwaves - 1) / nwaves;

  bag_mlp_v4<<<NBLOCKS, 256, 0, stream>>>(x, ids, W1, b1, W2, bag_sum,
                                          nchunks, cpw, nbags);
  bag_start_kernel<<<2048, 256, 0, stream>>>(ids, start, n);
  finalize_kernel<<<(nbags + 255) / 256, 256, 0, stream>>>(bag_sum, start, b2,
                                                           out, nbags, n);
}